// Round 1
// baseline (597.038 us; speedup 1.0000x reference)
//
#include <hip/hip_runtime.h>
#include <cstdint>
#include <cstddef>

// Problem constants (match reference)
static constexpr int BATCH = 32;
static constexpr int KJ    = 17;   // heat channels (joints)
static constexpr int LL    = 19;   // limbs
static constexpr int HH    = 160;
static constexpr int WW    = 160;
static constexpr int PPK   = 30;   // top-k peaks
static constexpr int SS    = 10;   // samples along limb
static constexpr int HW    = HH * WW;
static constexpr int CAP   = 4096; // candidate capacity per channel

__constant__ int d_ska[LL] = {15,13,16,14,11,5,6,5,5,6,7,8,1,0,0,1,2,3,4};
__constant__ int d_skb[LL] = {13,11,14,12,12,11,12,6,7,8,9,10,2,1,2,3,4,5,6};
// t = linspace(0,1,10) in f32 (verified identical to f32(s/9.0))
__constant__ float d_ts[SS] = {
    0.0f,
    (float)(1.0/9.0), (float)(2.0/9.0), (float)(3.0/9.0),
    (float)(4.0/9.0), (float)(5.0/9.0), (float)(6.0/9.0),
    (float)(7.0/9.0), (float)(8.0/9.0),
    1.0f
};

// ---------------------------------------------------------------------------
// Kernel 1: per-channel peak detection + top-30 + subpixel refine.
// One block per (b,k). Writes peaks (px,py,sc) into out[(ch*30+p)*3 + {0,1,2}].
// ---------------------------------------------------------------------------
__global__ __launch_bounds__(256) void peaks_kernel(const float* __restrict__ heat,
                                                    float* __restrict__ out)
{
    const int ch = blockIdx.x;              // b*17 + k
    const float* hp = heat + (size_t)ch * HW;

    __shared__ unsigned long long keys[CAP];
    __shared__ unsigned long long wred[4];
    __shared__ unsigned long long sel[PPK];
    __shared__ int cnt;

    const int tid = threadIdx.x;
    if (tid == 0) cnt = 0;
    __syncthreads();

    // ---- candidate scan: local max of clipped 3x3 window AND > 0.1 ----
    for (int idx = tid; idx < HW; idx += 256) {
        float v = hp[idx];
        if (!(v > 0.1f)) continue;
        int y = idx / WW;
        int x = idx - y * WW;
        int x0 = (x > 0) ? x - 1 : 0;
        int x1 = (x < WW - 1) ? x + 1 : WW - 1;
        int y0 = (y > 0) ? y - 1 : 0;
        int y1 = (y < HH - 1) ? y + 1 : HH - 1;
        bool peak = true;
        for (int yy = y0; yy <= y1 && peak; ++yy) {
            const float* row = hp + yy * WW;
            for (int xx = x0; xx <= x1; ++xx) {
                if (row[xx] > v) { peak = false; break; }
            }
        }
        if (peak) {
            int slot = atomicAdd(&cnt, 1);
            if (slot < CAP) {
                unsigned int vb = __float_as_uint(v);   // v > 0 -> order-preserving bits
                keys[slot] = ((unsigned long long)vb << 32)
                           | (unsigned long long)(0xFFFFFFFFu - (unsigned)idx);
            }
        }
    }
    __syncthreads();

    const int n = (cnt < CAP) ? cnt : CAP;

    // ---- iterative top-30 selection (max value, ties -> lowest index) ----
    for (int r = 0; r < PPK; ++r) {
        unsigned long long best = 0ull;
        for (int i = tid; i < n; i += 256) {
            unsigned long long k = keys[i];
            if (k > best) best = k;
        }
        // wave (64-lane) reduce
        #pragma unroll
        for (int off = 32; off > 0; off >>= 1) {
            unsigned long long o = __shfl_down(best, off);
            if (o > best) best = o;
        }
        if ((tid & 63) == 0) wred[tid >> 6] = best;
        __syncthreads();
        if (tid == 0) {
            unsigned long long g0 = wred[0] > wred[1] ? wred[0] : wred[1];
            unsigned long long g1 = wred[2] > wred[3] ? wred[2] : wred[3];
            sel[r] = g0 > g1 ? g0 : g1;
        }
        __syncthreads();
        unsigned long long g = sel[r];
        if (g != 0ull) {
            for (int i = tid; i < n; i += 256) {
                if (keys[i] == g) keys[i] = 0ull;
            }
        }
        __syncthreads();
    }

    // ---- emit peaks with subpixel refinement ----
    if (tid < PPK) {
        unsigned long long g = sel[tid];
        float px = 0.0f, py = 0.0f, sc = 0.0f;
        if (g != 0ull) {
            float v = __uint_as_float((unsigned int)(g >> 32));
            int idx = (int)(0xFFFFFFFFu - (unsigned int)(g & 0xFFFFFFFFull));
            int y = idx / WW;
            int x = idx - y * WW;
            float dx = 0.0f, dy = 0.0f;
            if (x > 0 && x < WW - 1 && y > 0 && y < HH - 1) {
                float r_ = hp[y * WW + x + 1];
                float l_ = hp[y * WW + x - 1];
                float dn = hp[(y + 1) * WW + x];
                float up = hp[(y - 1) * WW + x];
                float dx_raw = 0.5f * (r_ - l_);
                float dy_raw = 0.5f * (dn - up);
                float dxx = __fsub_rn(__fadd_rn(r_, l_), 2.0f * v);
                float dyy = __fsub_rn(__fadd_rn(dn, up), 2.0f * v);
                dx = (fabsf(dxx) > 1e-6f) ? (dx_raw / (-dxx)) : dx_raw;
                dy = (fabsf(dyy) > 1e-6f) ? (dy_raw / (-dyy)) : dy_raw;
            }
            px = __fadd_rn((float)x, dx);
            py = __fadd_rn((float)y, dy);
            sc = v;
        }
        float* o = out + ((size_t)ch * PPK + tid) * 3;
        o[0] = px;
        o[1] = py;
        o[2] = sc;
    }
}

// ---------------------------------------------------------------------------
// Kernel 2: PAF connection scoring. One block per (b,l); 900 pairs/block.
// peaks: [B,17,30,3] (px,py,sc) as written by kernel 1.
// conn:  [B,19,30,30]
// ---------------------------------------------------------------------------
__global__ __launch_bounds__(256) void conn_kernel(const float* __restrict__ paf,
                                                   const float* __restrict__ peaks,
                                                   float* __restrict__ conn)
{
    const int bl = blockIdx.x;        // b*19 + l
    const int b  = bl / LL;
    const int l  = bl - b * LL;

    const float* pafx = paf + (((size_t)b * (2 * LL)) + 2 * l) * HW;
    const float* pafy = pafx + HW;

    __shared__ float As[PPK * 3];
    __shared__ float Bs[PPK * 3];

    const int tid = threadIdx.x;
    {
        const float* pa = peaks + (((size_t)b * KJ) + d_ska[l]) * (PPK * 3);
        const float* pb = peaks + (((size_t)b * KJ) + d_skb[l]) * (PPK * 3);
        if (tid < PPK * 3)            As[tid] = pa[tid];
        else if (tid < 2 * PPK * 3)   Bs[tid - PPK * 3] = pb[tid - PPK * 3];
    }
    __syncthreads();

    float* co = conn + (size_t)bl * (PPK * PPK);

    for (int p = tid; p < PPK * PPK; p += 256) {
        int i = p / PPK;          // a-peak index (dim 2)
        int j = p - i * PPK;      // b-peak index (dim 3)

        float ax = As[i * 3 + 0], ay = As[i * 3 + 1], sa = As[i * 3 + 2];
        float bx = Bs[j * 3 + 0], by = Bs[j * 3 + 1], sb = Bs[j * 3 + 2];
        bool va = sa > 0.1f;
        bool vb = sb > 0.1f;

        float dxl = __fsub_rn(bx, ax);
        float dyl = __fsub_rn(by, ay);
        float nsq = __fadd_rn(__fmul_rn(dxl, dxl), __fmul_rn(dyl, dyl));
        float nrm = __fadd_rn(sqrtf(nsq), 1e-8f);
        float vx  = dxl / nrm;
        float vy  = dyl / nrm;

        float vs[SS];
        int   cntc = 0;
        #pragma unroll
        for (int s = 0; s < SS; ++s) {
            float t  = d_ts[s];
            float xs = __fadd_rn(ax, __fmul_rn(t, dxl));
            float ys = __fadd_rn(ay, __fmul_rn(t, dyl));
            float rx = rintf(xs);               // round half to even, matches jnp.round
            float ry = rintf(ys);
            rx = fminf(fmaxf(rx, 0.0f), (float)(WW - 1));
            ry = fminf(fmaxf(ry, 0.0f), (float)(HH - 1));
            int ix = (int)rx;
            int iy = (int)ry;
            int lin = iy * WW + ix;
            float vxs = pafx[lin];
            float vys = pafy[lin];
            float vec = __fadd_rn(__fmul_rn(vxs, vx), __fmul_rn(vys, vy));
            vs[s] = vec;
            if (vec > 0.05f) ++cntc;
        }
        // numpy pairwise order for n=10: tree over first 8, then sequential
        float s01 = __fadd_rn(vs[0], vs[1]);
        float s23 = __fadd_rn(vs[2], vs[3]);
        float s45 = __fadd_rn(vs[4], vs[5]);
        float s67 = __fadd_rn(vs[6], vs[7]);
        float sum = __fadd_rn(__fadd_rn(s01, s23), __fadd_rn(s45, s67));
        sum = __fadd_rn(sum, vs[8]);
        sum = __fadd_rn(sum, vs[9]);
        float mean = sum / 10.0f;

        bool cond = (mean > 0.0f) && (cntc >= 9) && va && vb;  // ratio>0.8 <=> cnt>=9 in f32
        float val = 0.0f;
        if (cond) {
            val = __fadd_rn(mean, __fmul_rn(0.5f, __fadd_rn(sa, sb)));
        }
        co[p] = val;
    }
}

extern "C" void kernel_launch(void* const* d_in, const int* in_sizes, int n_in,
                              void* d_out, int out_size, void* d_ws, size_t ws_size,
                              hipStream_t stream)
{
    const float* heat = (const float*)d_in[0];   // [32,17,160,160]
    const float* paf  = (const float*)d_in[1];   // [32,38,160,160]
    float* out = (float*)d_out;

    float* peaks_out = out;                                   // 32*17*30*3 = 48960
    float* conn_out  = out + (size_t)BATCH * KJ * PPK * 3;    // 32*19*30*30 = 547200

    hipLaunchKernelGGL(peaks_kernel, dim3(BATCH * KJ), dim3(256), 0, stream,
                       heat, peaks_out);
    hipLaunchKernelGGL(conn_kernel, dim3(BATCH * LL), dim3(256), 0, stream,
                       paf, peaks_out, conn_out);
}

// Round 2
// 302.324 us; speedup vs baseline: 1.9748x; 1.9748x over previous
//
#include <hip/hip_runtime.h>
#include <cstdint>
#include <cstddef>
#include <cfloat>

// Problem constants (match reference)
static constexpr int BATCH = 32;
static constexpr int KJ    = 17;   // heat channels (joints)
static constexpr int LL    = 19;   // limbs
static constexpr int HH    = 160;
static constexpr int WW    = 160;
static constexpr int PPK   = 30;   // top-k peaks
static constexpr int SS    = 10;   // samples along limb
static constexpr int HW    = HH * WW;
static constexpr int CAP   = 4096; // candidate capacity per channel (LDS)
static constexpr int CELLS = HW / 4;       // 6400 float4 cells per channel
static constexpr int CGW   = WW / 4;       // 40 cell-groups per row

__constant__ int d_ska[LL] = {15,13,16,14,11,5,6,5,5,6,7,8,1,0,0,1,2,3,4};
__constant__ int d_skb[LL] = {13,11,14,12,12,11,12,6,7,8,9,10,2,1,2,3,4,5,6};
// t = linspace(0,1,10) in f32 (verified identical to f32(s/9.0))
__constant__ float d_ts[SS] = {
    0.0f,
    (float)(1.0/9.0), (float)(2.0/9.0), (float)(3.0/9.0),
    (float)(4.0/9.0), (float)(5.0/9.0), (float)(6.0/9.0),
    (float)(7.0/9.0), (float)(8.0/9.0),
    1.0f
};

__device__ __forceinline__ float max3f(float a, float b, float c) {
    return fmaxf(fmaxf(a, b), c);
}
__device__ __forceinline__ unsigned long long umax64(unsigned long long a, unsigned long long b) {
    return a > b ? a : b;
}

// ---------------------------------------------------------------------------
// Kernel 1: per-channel peak detection + top-30 + subpixel refine.
// One block per (b,k). Branchless separable 3x3 max scan over float4 cells;
// ballot-aggregated candidate append; register-resident per-wave top-30 with
// a single-wave 120->30 merge. Writes (px,py,sc) into out[(ch*30+p)*3+{0,1,2}].
// ---------------------------------------------------------------------------
__global__ __launch_bounds__(256, 4) void peaks_kernel(const float* __restrict__ heat,
                                                       float* __restrict__ out)
{
    const int ch = blockIdx.x;              // b*17 + k
    const float* hp = heat + (size_t)ch * HW;

    __shared__ unsigned long long keys[CAP];
    __shared__ unsigned long long sel4[4 * PPK];
    __shared__ unsigned long long sel[PPK];
    __shared__ int cnt;

    const int tid  = threadIdx.x;
    const int lane = tid & 63;
    const int wave = tid >> 6;
    const unsigned long long ltmask = ((unsigned long long)1 << lane) - 1ull;

    if (tid == 0) cnt = 0;
    __syncthreads();

    // ---- branchless scan: 25 float4 cells per thread ----
    for (int c = tid; c < CELLS; c += 256) {
        int y  = c / CGW;
        int cg = c - y * CGW;
        int x0 = cg * 4;
        int yu = (y > 0) ? y - 1 : 0;
        int yd = (y < HH - 1) ? y + 1 : HH - 1;

        const float* rc = hp + y  * WW + x0;
        const float* ru = hp + yu * WW + x0;
        const float* rd = hp + yd * WW + x0;

        float4 vc = *(const float4*)rc;
        float4 vu = *(const float4*)ru;
        float4 vd = *(const float4*)rd;
        bool hasL = (x0 > 0);
        bool hasR = (x0 + 4 < WW);
        float lc = hasL ? rc[-1] : -FLT_MAX;
        float lu = hasL ? ru[-1] : -FLT_MAX;
        float ld = hasL ? rd[-1] : -FLT_MAX;
        float rcx = hasR ? rc[4] : -FLT_MAX;
        float rux = hasR ? ru[4] : -FLT_MAX;
        float rdx = hasR ? rd[4] : -FLT_MAX;

        // per-row horizontal 3-max at the 4 positions
        float mu0 = max3f(lu, vu.x, vu.y), mu1 = max3f(vu.x, vu.y, vu.z);
        float mu2 = max3f(vu.y, vu.z, vu.w), mu3 = max3f(vu.z, vu.w, rux);
        float mc0 = max3f(lc, vc.x, vc.y), mc1 = max3f(vc.x, vc.y, vc.z);
        float mc2 = max3f(vc.y, vc.z, vc.w), mc3 = max3f(vc.z, vc.w, rcx);
        float md0 = max3f(ld, vd.x, vd.y), md1 = max3f(vd.x, vd.y, vd.z);
        float md2 = max3f(vd.y, vd.z, vd.w), md3 = max3f(vd.z, vd.w, rdx);

        float nm0 = max3f(mu0, mc0, md0);
        float nm1 = max3f(mu1, mc1, md1);
        float nm2 = max3f(mu2, mc2, md2);
        float nm3 = max3f(mu3, mc3, md3);

        bool pk0 = (vc.x == nm0) && (vc.x > 0.1f);
        bool pk1 = (vc.y == nm1) && (vc.y > 0.1f);
        bool pk2 = (vc.z == nm2) && (vc.z > 0.1f);
        bool pk3 = (vc.w == nm3) && (vc.w > 0.1f);

        // ballot-aggregated append (order within wave irrelevant: keys carry idx)
        unsigned long long b0 = __ballot(pk0);
        unsigned long long b1 = __ballot(pk1);
        unsigned long long b2 = __ballot(pk2);
        unsigned long long b3 = __ballot(pk3);
        int c0 = __popcll(b0), c1 = __popcll(b1), c2 = __popcll(b2), c3 = __popcll(b3);
        int tot = c0 + c1 + c2 + c3;
        int base = 0;
        if (lane == 0 && tot > 0) base = atomicAdd(&cnt, tot);
        base = __shfl(base, 0);

        int idx0 = y * WW + x0;
        if (pk0) {
            int slot = base + __popcll(b0 & ltmask);
            if (slot < CAP)
                keys[slot] = ((unsigned long long)__float_as_uint(vc.x) << 32)
                           | (unsigned long long)(0xFFFFFFFFu - (unsigned)(idx0 + 0));
        }
        if (pk1) {
            int slot = base + c0 + __popcll(b1 & ltmask);
            if (slot < CAP)
                keys[slot] = ((unsigned long long)__float_as_uint(vc.y) << 32)
                           | (unsigned long long)(0xFFFFFFFFu - (unsigned)(idx0 + 1));
        }
        if (pk2) {
            int slot = base + c0 + c1 + __popcll(b2 & ltmask);
            if (slot < CAP)
                keys[slot] = ((unsigned long long)__float_as_uint(vc.z) << 32)
                           | (unsigned long long)(0xFFFFFFFFu - (unsigned)(idx0 + 2));
        }
        if (pk3) {
            int slot = base + c0 + c1 + c2 + __popcll(b3 & ltmask);
            if (slot < CAP)
                keys[slot] = ((unsigned long long)__float_as_uint(vc.w) << 32)
                           | (unsigned long long)(0xFFFFFFFFu - (unsigned)(idx0 + 3));
        }
    }
    __syncthreads();

    const int n = (cnt < CAP) ? cnt : CAP;

    // ---- per-wave top-30 over its 1024-key chunk, register-resident ----
    unsigned long long k[16];
    {
        int base0 = wave * 1024 + lane;
        #pragma unroll
        for (int i = 0; i < 16; ++i) {
            int p = base0 + i * 64;
            k[i] = (p < n) ? keys[p] : 0ull;
        }
    }
    for (int r = 0; r < PPK; ++r) {
        unsigned long long best = k[0];
        #pragma unroll
        for (int i = 1; i < 16; ++i) best = umax64(best, k[i]);
        #pragma unroll
        for (int off = 1; off < 64; off <<= 1)
            best = umax64(best, (unsigned long long)__shfl_xor((long long)best, off));
        // best == wave-chunk max on all lanes
        if (best != 0ull) {
            #pragma unroll
            for (int i = 0; i < 16; ++i)
                if (k[i] == best) k[i] = 0ull;   // keys unique when nonzero
        }
        if (lane == 0) sel4[wave * PPK + r] = best;
    }
    __syncthreads();

    // ---- wave 0 merges 120 -> 30 ----
    if (wave == 0) {
        unsigned long long m0 = sel4[lane];                       // lanes 0..63
        unsigned long long m1 = (lane + 64 < 4 * PPK) ? sel4[lane + 64] : 0ull;
        for (int r = 0; r < PPK; ++r) {
            unsigned long long best = umax64(m0, m1);
            #pragma unroll
            for (int off = 1; off < 64; off <<= 1)
                best = umax64(best, (unsigned long long)__shfl_xor((long long)best, off));
            if (best != 0ull) {
                if (m0 == best) m0 = 0ull;
                else if (m1 == best) m1 = 0ull;
            }
            if (lane == 0) sel[r] = best;
        }
    }
    __syncthreads();

    // ---- emit peaks with subpixel refinement (identical math to validated R1) ----
    if (tid < PPK) {
        unsigned long long g = sel[tid];
        float px = 0.0f, py = 0.0f, sc = 0.0f;
        if (g != 0ull) {
            float v = __uint_as_float((unsigned int)(g >> 32));
            int idx = (int)(0xFFFFFFFFu - (unsigned int)(g & 0xFFFFFFFFull));
            int y = idx / WW;
            int x = idx - y * WW;
            float dx = 0.0f, dy = 0.0f;
            if (x > 0 && x < WW - 1 && y > 0 && y < HH - 1) {
                float r_ = hp[y * WW + x + 1];
                float l_ = hp[y * WW + x - 1];
                float dn = hp[(y + 1) * WW + x];
                float up = hp[(y - 1) * WW + x];
                float dx_raw = 0.5f * (r_ - l_);
                float dy_raw = 0.5f * (dn - up);
                float dxx = __fsub_rn(__fadd_rn(r_, l_), 2.0f * v);
                float dyy = __fsub_rn(__fadd_rn(dn, up), 2.0f * v);
                dx = (fabsf(dxx) > 1e-6f) ? (dx_raw / (-dxx)) : dx_raw;
                dy = (fabsf(dyy) > 1e-6f) ? (dy_raw / (-dyy)) : dy_raw;
            }
            px = __fadd_rn((float)x, dx);
            py = __fadd_rn((float)y, dy);
            sc = v;
        }
        float* o = out + ((size_t)ch * PPK + tid) * 3;
        o[0] = px;
        o[1] = py;
        o[2] = sc;
    }
}

// ---------------------------------------------------------------------------
// Kernel 2: PAF connection scoring. One block per (b,l,quarter); 225 pairs,
// one pair per thread. peaks: [B,17,30,3]; conn: [B,19,30,30].
// ---------------------------------------------------------------------------
__global__ __launch_bounds__(256) void conn_kernel(const float* __restrict__ paf,
                                                   const float* __restrict__ peaks,
                                                   float* __restrict__ conn)
{
    const int blk = blockIdx.x;       // (b*19 + l)*4 + q
    const int bl  = blk >> 2;
    const int q   = blk & 3;
    const int b   = bl / LL;
    const int l   = bl - b * LL;

    const float* pafx = paf + (((size_t)b * (2 * LL)) + 2 * l) * HW;
    const float* pafy = pafx + HW;

    __shared__ float As[PPK * 3];
    __shared__ float Bs[PPK * 3];

    const int tid = threadIdx.x;
    {
        const float* pa = peaks + (((size_t)b * KJ) + d_ska[l]) * (PPK * 3);
        const float* pb = peaks + (((size_t)b * KJ) + d_skb[l]) * (PPK * 3);
        if (tid < PPK * 3)            As[tid] = pa[tid];
        else if (tid < 2 * PPK * 3)   Bs[tid - PPK * 3] = pb[tid - PPK * 3];
    }
    __syncthreads();

    const int p = q * 225 + tid;      // 225 pairs per quarter, tid < 225
    if (tid < 225 && p < PPK * PPK) {
        int i = p / PPK;          // a-peak index (dim 2)
        int j = p - i * PPK;      // b-peak index (dim 3)

        float ax = As[i * 3 + 0], ay = As[i * 3 + 1], sa = As[i * 3 + 2];
        float bx = Bs[j * 3 + 0], by = Bs[j * 3 + 1], sb = Bs[j * 3 + 2];
        bool va = sa > 0.1f;
        bool vb = sb > 0.1f;

        float dxl = __fsub_rn(bx, ax);
        float dyl = __fsub_rn(by, ay);
        float nsq = __fadd_rn(__fmul_rn(dxl, dxl), __fmul_rn(dyl, dyl));
        float nrm = __fadd_rn(sqrtf(nsq), 1e-8f);
        float vx  = dxl / nrm;
        float vy  = dyl / nrm;

        float vs[SS];
        int   cntc = 0;
        #pragma unroll
        for (int s = 0; s < SS; ++s) {
            float t  = d_ts[s];
            float xs = __fadd_rn(ax, __fmul_rn(t, dxl));
            float ys = __fadd_rn(ay, __fmul_rn(t, dyl));
            float rx = rintf(xs);               // round half to even, matches jnp.round
            float ry = rintf(ys);
            rx = fminf(fmaxf(rx, 0.0f), (float)(WW - 1));
            ry = fminf(fmaxf(ry, 0.0f), (float)(HH - 1));
            int ix = (int)rx;
            int iy = (int)ry;
            int lin = iy * WW + ix;
            float vxs = pafx[lin];
            float vys = pafy[lin];
            float vec = __fadd_rn(__fmul_rn(vxs, vx), __fmul_rn(vys, vy));
            vs[s] = vec;
            if (vec > 0.05f) ++cntc;
        }
        // numpy pairwise order for n=10: tree over first 8, then sequential
        float s01 = __fadd_rn(vs[0], vs[1]);
        float s23 = __fadd_rn(vs[2], vs[3]);
        float s45 = __fadd_rn(vs[4], vs[5]);
        float s67 = __fadd_rn(vs[6], vs[7]);
        float sum = __fadd_rn(__fadd_rn(s01, s23), __fadd_rn(s45, s67));
        sum = __fadd_rn(sum, vs[8]);
        sum = __fadd_rn(sum, vs[9]);
        float mean = sum / 10.0f;

        bool cond = (mean > 0.0f) && (cntc >= 9) && va && vb;  // ratio>0.8 <=> cnt>=9 in f32
        float val = 0.0f;
        if (cond) {
            val = __fadd_rn(mean, __fmul_rn(0.5f, __fadd_rn(sa, sb)));
        }
        conn[(size_t)bl * (PPK * PPK) + p] = val;
    }
}

extern "C" void kernel_launch(void* const* d_in, const int* in_sizes, int n_in,
                              void* d_out, int out_size, void* d_ws, size_t ws_size,
                              hipStream_t stream)
{
    const float* heat = (const float*)d_in[0];   // [32,17,160,160]
    const float* paf  = (const float*)d_in[1];   // [32,38,160,160]
    float* out = (float*)d_out;

    float* peaks_out = out;                                   // 32*17*30*3 = 48960
    float* conn_out  = out + (size_t)BATCH * KJ * PPK * 3;    // 32*19*30*30 = 547200

    hipLaunchKernelGGL(peaks_kernel, dim3(BATCH * KJ), dim3(256), 0, stream,
                       heat, peaks_out);
    hipLaunchKernelGGL(conn_kernel, dim3(BATCH * LL * 4), dim3(256), 0, stream,
                       paf, peaks_out, conn_out);
}